// Round 1
// 69.673 us; speedup vs baseline: 1.0078x; 1.0078x over previous
//
#include <hip/hip_runtime.h>
#include <math.h>

#define BB 4
#define LL 512
#define DD 128
#define TQ 8                  // queries per block
#define NROW (TQ + 2)         // 10 staged x rows (with halo)
#define NS 4                  // split-K slices
#define KPT (DD / NS)         // 32 K-values per thread
#define PROWS (NROW + TQ)     // 18 GEMV outputs: 0..9 = k rows, 10..17 = q rows
#define EPSV 1e-8f

__device__ __forceinline__ float fast_tanh(float v) {
    float e = __expf(2.0f * v);
    return 1.0f - 2.0f / (e + 1.0f);
}

// One matrix per thread (mat = g&1), KPT=32 -> 32 weight VGPRs instead of 64.
// Peak live regs ~85 (was ~120 at the 128 cap) -> compiler can pipeline GEMV.
__global__ __launch_bounds__(1024, 4) void additive_emission_kernel(
    const float* __restrict__ x,   // [B,L,D]
    const float* __restrict__ Wt,  // [D,D] row-major [d_in][d_out]
    const float* __restrict__ Wx,  // [D,D]
    const float* __restrict__ Wa,  // [D]
    const float* __restrict__ bh,  // [D]
    const float* __restrict__ ba,  // [1]  (cancels in softmax -> unused)
    float* __restrict__ out)       // [B,L,D]
{
    __shared__ float xs[NROW][DD];
    __shared__ float part[NS][PROWS][DD];   // 36 KB
    __shared__ float shbh[DD];
    __shared__ float shwa[DD];
    __shared__ float score[TQ * 3];

    const int t = threadIdx.x;
    const int c = t & 127;            // output column
    const int g = t >> 7;             // 0..7, wave-uniform (2 waves per group)
    const int mat = g & 1;            // 0 -> Wx (k rows), 1 -> Wt (q rows)
    const int s = g >> 1;             // split-K slice 0..3
    const int dp0 = s * KPT;
    const int b = blockIdx.x >> 6;    // 64 tiles per batch
    const int tile = blockIdx.x & 63;
    const int i0 = tile * TQ;
    const int jlo = i0 - 1;

    // ---- issue weight loads first; latency overlaps staging + barrier ----
    float w[KPT];
    {
        const float* __restrict__ wp = (mat ? Wt : Wx) + (size_t)dp0 * DD + c;
        #pragma unroll
        for (int k = 0; k < KPT; ++k) w[k] = wp[(size_t)k * DD];
    }

    if (t < NROW * (DD / 4)) {        // 320 threads stage 10 x rows as float4
        int r = t >> 5, c4 = t & 31;
        int j = jlo + r;
        float4 v = make_float4(0.f, 0.f, 0.f, 0.f);
        if (j >= 0 && j < LL)
            v = ((const float4*)x)[(size_t)(b * LL + j) * (DD / 4) + c4];
        ((float4*)xs[r])[c4] = v;
    }
    if (t >= 512 && t < 512 + DD) shbh[t - 512] = bh[t - 512];
    if (t >= 768 && t < 768 + DD) shwa[t - 768] = Wa[t - 768];
    __syncthreads();

    // ---- GEMV: LDS-broadcast x  ×  register weights (one matrix each) ----
    if (mat == 0) {                   // k projection: 10 rows
        float acc[NROW];
        #pragma unroll
        for (int r = 0; r < NROW; ++r) acc[r] = 0.f;
        #pragma unroll
        for (int ch = 0; ch < KPT / 4; ++ch) {
            float4 xv[NROW];
            #pragma unroll
            for (int r = 0; r < NROW; ++r)
                xv[r] = ((const float4*)xs[r])[s * (KPT / 4) + ch];  // wave-uniform bcast
            const int kk = ch * 4;
            float w0 = w[kk], w1 = w[kk + 1], w2 = w[kk + 2], w3 = w[kk + 3];
            #pragma unroll
            for (int r = 0; r < NROW; ++r)
                acc[r] = fmaf(xv[r].w, w3, fmaf(xv[r].z, w2,
                         fmaf(xv[r].y, w1, fmaf(xv[r].x, w0, acc[r]))));
        }
        #pragma unroll
        for (int r = 0; r < NROW; ++r) part[s][r][c] = acc[r];
    } else {                          // q projection: 8 rows (xs rows 1..8)
        float acc[TQ];
        #pragma unroll
        for (int r = 0; r < TQ; ++r) acc[r] = 0.f;
        #pragma unroll
        for (int ch = 0; ch < KPT / 4; ++ch) {
            float4 xv[TQ];
            #pragma unroll
            for (int r = 0; r < TQ; ++r)
                xv[r] = ((const float4*)xs[r + 1])[s * (KPT / 4) + ch];
            const int kk = ch * 4;
            float w0 = w[kk], w1 = w[kk + 1], w2 = w[kk + 2], w3 = w[kk + 3];
            #pragma unroll
            for (int r = 0; r < TQ; ++r)
                acc[r] = fmaf(xv[r].w, w3, fmaf(xv[r].z, w2,
                         fmaf(xv[r].y, w1, fmaf(xv[r].x, w0, acc[r]))));
        }
        #pragma unroll
        for (int r = 0; r < TQ; ++r) part[s][NROW + r][c] = acc[r];
    }
    __syncthreads();

    // ---- scores: 24 (query, offset) pairs over 16 waves ----
    const int wv = t >> 6;
    const int lane = t & 63;
    for (int p = wv; p < TQ * 3; p += 16) {
        int qi = p / 3, jj = p - qi * 3;
        int j = i0 + qi - 1 + jj;          // global key index
        float sum;
        if (j >= 0 && j < LL) {            // wave-uniform branch
            int r = qi + jj;               // k row in part (0..9)
            sum = 0.0f;
            #pragma unroll
            for (int u = 0; u < 2; ++u) {
                int d = lane + u * 64;
                float qv = part[0][NROW + qi][d] + part[1][NROW + qi][d]
                         + part[2][NROW + qi][d] + part[3][NROW + qi][d];
                float kv = part[0][r][d] + part[1][r][d]
                         + part[2][r][d] + part[3][r][d];
                sum += fast_tanh(qv + kv + shbh[d]) * shwa[d];
            }
            #pragma unroll
            for (int off = 32; off > 0; off >>= 1)
                sum += __shfl_xor(sum, off, 64);
        } else {
            sum = -1e30f;
        }
        if (lane == 0) score[p] = sum;
    }
    __syncthreads();

    // ---- output: per-thread redundant 3-term softmax + weighted sum ----
    {
        int qi = t >> 7;                   // 0..7 (wave-uniform), c = t&127
        float s0 = score[qi * 3 + 0], s1 = score[qi * 3 + 1], s2 = score[qi * 3 + 2];
        float m = fmaxf(s0, fmaxf(s1, s2));
        float e0 = (s0 > -1e29f) ? __expf(s0 - m) : 0.0f;
        float e1 = (s1 > -1e29f) ? __expf(s1 - m) : 0.0f;
        float e2 = (s2 > -1e29f) ? __expf(s2 - m) : 0.0f;
        float inv = 1.0f / (e0 + e1 + e2 + EPSV);
        float v = (e0 * xs[qi][c] + e1 * xs[qi + 1][c] + e2 * xs[qi + 2][c]) * inv;
        out[(size_t)(b * LL + i0 + qi) * DD + c] = v;
    }
}

extern "C" void kernel_launch(void* const* d_in, const int* in_sizes, int n_in,
                              void* d_out, int out_size, void* d_ws, size_t ws_size,
                              hipStream_t stream) {
    const float* x  = (const float*)d_in[0];
    const float* Wt = (const float*)d_in[1];
    const float* Wx = (const float*)d_in[2];
    const float* Wa = (const float*)d_in[3];
    const float* bh = (const float*)d_in[4];
    const float* ba = (const float*)d_in[5];
    float* out = (float*)d_out;

    dim3 grid(BB * (LL / TQ));   // 256 blocks -> 1 block/CU, 16 waves/CU
    additive_emission_kernel<<<grid, 1024, 0, stream>>>(x, Wt, Wx, Wa, bh, ba, out);
}